// Round 1
// baseline (466.873 us; speedup 1.0000x reference)
//
#include <hip/hip_runtime.h>

// t-product forward: out = relu(bcirc(W) @ X + B)
// X: [784][65536] fp32 (x flat), A = bcirc(W): [784][784], out: [784][65536] fp32.
// Strategy: prep kernel builds A as bf16 in d_ws, pre-tiled in LDS staging order;
// main kernel is a 112x256-tile bf16 MFMA GEMM with fused fp32->bf16 conversion
// of X during reg-staged LDS writes (XOR-swizzled, conflict-free).

typedef __attribute__((ext_vector_type(4))) float f32x4;
typedef __attribute__((ext_vector_type(8))) short s16x8;
typedef __attribute__((ext_vector_type(4))) unsigned int u32x4;

#define BATCH    65536
#define MROWS    784
#define KDIM     784
#define KSTEPS   25            // K padded to 800, BK=32
#define BM       112           // 7 x 16; 784/112 = 7 exact (no M padding)
#define BN       256
#define MT       7
#define NT       256           // 65536/256
#define NWG      (MT*NT)       // 1792 (divisible by 8 -> bijective XCD swizzle)
#define ATILE_ELEMS 3584       // [kb=4][m=112][e=8] bf16 = 7168 B per (mt,ks) tile
#define AWS_ELEMS  (MT*KSTEPS*ATILE_ELEMS)  // 627200 elems = 1.25 MB

// round-to-nearest-even f32 -> bf16 (bias-free; truncation bias would accumulate
// over the 784-term dot product)
__device__ __forceinline__ unsigned int rne1(float f) {
  unsigned int u = __float_as_uint(f);
  return (u + 0x7fffu + ((u >> 16) & 1u)) >> 16;
}
__device__ __forceinline__ unsigned int pack2(float a, float b) {
  return rne1(a) | (rne1(b) << 16);
}

typedef const __attribute__((address_space(1))) unsigned int glb_uint;
typedef __attribute__((address_space(3))) unsigned int lds_uint;
__device__ __forceinline__ void async16(const void* g, void* l) {
  // 16B-wide direct global->LDS; dest = wave-uniform base + lane*16
  __builtin_amdgcn_global_load_lds((glb_uint*)g, (lds_uint*)l, 16, 0, 0);
}

// Build A_ws[(mt*25+ks)] tiles, each laid out exactly as the GEMM's A-LDS:
// linear index o = (kb*112 + m)*8 + e  <->  A[row = mt*112+m][k = ks*32 + kb*8 + e]
__global__ void build_A(const float* __restrict__ W, unsigned short* __restrict__ A_ws) {
  int idx = blockIdx.x * 256 + threadIdx.x;
  if (idx >= AWS_ELEMS) return;
  int tile = idx / ATILE_ELEMS;
  int o    = idx - tile * ATILE_ELEMS;
  int mt   = tile / KSTEPS;
  int ks   = tile - mt * KSTEPS;
  int e    = o & 7;
  int slot = o >> 3;
  int kb   = slot / BM;
  int ml   = slot - kb * BM;
  int r    = mt * BM + ml;            // 0..783
  int c    = ks * 32 + kb * 8 + e;    // 0..799 (zero-pad K 784..799)
  float v = 0.0f;
  if (c < KDIM) {
    int kl = r / 28, mm = r - kl * 28;
    int j  = c / 28, n  = c - j * 28;
    int d = kl - j; if (d < 0) d += 28;
    v = W[(d * 28 + mm) * 28 + n];
  }
  A_ws[idx] = (unsigned short)rne1(v);
}

__global__ __launch_bounds__(256, 2) void tnn_gemm(
    const float* __restrict__ X, const unsigned short* __restrict__ A_ws,
    const float* __restrict__ Bias, float* __restrict__ C) {
  // A: [kb=4][m=112][e=8] bf16, linear (global_load_lds dest must be linear)
  __shared__ __align__(16) unsigned short a_lds[ATILE_ELEMS];   // 7168 B
  // X: slot = kb*256 + n, 8 bf16 (k = kb*8+e) per 16B slot, XOR-swizzled
  __shared__ __align__(16) unsigned short x_lds[8192];          // 16384 B

  int bid = blockIdx.x;
  // XCD-aware bijective swizzle: each XCD gets 224 contiguous wgids (32 nt x 7 mt)
  int wg  = (bid & 7) * (NWG / 8) + (bid >> 3);
  int nt  = wg / MT;
  int mt  = wg - nt * MT;

  int tid  = threadIdx.x;
  int lane = tid & 63;
  int wave = tid >> 6;          // 4 waves; wave-tile = 112 x 64

  f32x4 acc[7][4];
#pragma unroll
  for (int i = 0; i < 7; ++i)
#pragma unroll
    for (int j = 0; j < 4; ++j)
      acc[i][j] = (f32x4){0.f, 0.f, 0.f, 0.f};

  // X staging: thread owns (n4 = lane -> 4 cols, kb = wave -> 8 rows)
  const float* xbase = X + (size_t)(nt * BN) + ((size_t)(wave * 8) << 16) + (lane << 2);
  int wslot0 = wave * 256 + (lane << 2);

  // fragment read addressing
  int a_rd    = (((lane >> 4) * BM) + (lane & 15)) * 16;          // + i*256 per m-frag
  int x_slot0 = (lane >> 4) * 256 + wave * 64 + (lane & 15);      // + jn*16 per n-frag

  for (int ks = 0; ks < KSTEPS; ++ks) {
    // --- global X loads to regs (no LDS hazard; overlaps prev MFMA + barrier) ---
    f32x4 v[8];
    int k0 = ks * 32 + wave * 8;
    const float* xs = xbase + ((size_t)ks << 21);   // + ks*32 rows
#pragma unroll
    for (int dk = 0; dk < 8; ++dk) {
      if (k0 + dk < KDIM) v[dk] = *(const f32x4*)(xs + ((size_t)dk << 16));
      else                v[dk] = (f32x4){0.f, 0.f, 0.f, 0.f};   // K zero-pad
    }

    __syncthreads();   // previous step's ds_reads complete -> safe to overwrite LDS

    // --- stage A: async direct-to-LDS, 7 x 1KB chunks across 4 waves ---
    const unsigned short* atile = A_ws + (size_t)(mt * KSTEPS + ks) * ATILE_ELEMS;
    async16(atile + wave * 512 + lane * 8, &a_lds[wave * 512]);
    if (wave < 3)
      async16(atile + (wave + 4) * 512 + lane * 8, &a_lds[(wave + 4) * 512]);

    // --- stage X: RNE cvt + 8x4 transpose-pack + swizzled ds_write_b128 ---
#pragma unroll
    for (int di = 0; di < 4; ++di) {
      int slot = wslot0 + di;
      int boff = (slot * 16) ^ (((slot >> 5) & 7) << 4);
      u32x4 w;
      w.x = pack2(v[0][di], v[1][di]);
      w.y = pack2(v[2][di], v[3][di]);
      w.z = pack2(v[4][di], v[5][di]);
      w.w = pack2(v[6][di], v[7][di]);
      *(u32x4*)((char*)x_lds + boff) = w;
    }

    __syncthreads();   // staging drained (compiler emits vmcnt(0) lgkmcnt(0))

    // --- compute: 7 A-frags + 4 B-frags -> 28 MFMAs ---
    s16x8 af[7], xf[4];
#pragma unroll
    for (int i = 0; i < 7; ++i)
      af[i] = *(const s16x8*)((const char*)a_lds + a_rd + i * 256);
#pragma unroll
    for (int jn = 0; jn < 4; ++jn) {
      int slot = x_slot0 + jn * 16;
      int boff = (slot * 16) ^ (((slot >> 5) & 7) << 4);
      xf[jn] = *(const s16x8*)((const char*)x_lds + boff);
    }
#pragma unroll
    for (int i = 0; i < 7; ++i)
#pragma unroll
      for (int jn = 0; jn < 4; ++jn)
        acc[i][jn] = __builtin_amdgcn_mfma_f32_16x16x32_bf16(af[i], xf[jn], acc[i][jn], 0, 0, 0);
  }

  // --- epilogue: + bias, relu, store ---
  int colbase = nt * BN + wave * 64 + (lane & 15);
#pragma unroll
  for (int i = 0; i < 7; ++i) {
    int r0 = mt * BM + i * 16 + ((lane >> 4) << 2);   // D row = (lane>>4)*4 + d
    f32x4 bv = *(const f32x4*)&Bias[r0];
#pragma unroll
    for (int jn = 0; jn < 4; ++jn) {
      size_t cb = ((size_t)r0 << 16) + (size_t)(colbase + jn * 16);
#pragma unroll
      for (int d = 0; d < 4; ++d) {
        float vv = acc[i][jn][d] + bv[d];
        C[cb + ((size_t)d << 16)] = fmaxf(vv, 0.0f);
      }
    }
  }
}

extern "C" void kernel_launch(void* const* d_in, const int* in_sizes, int n_in,
                              void* d_out, int out_size, void* d_ws, size_t ws_size,
                              hipStream_t stream) {
  const float* x  = (const float*)d_in[0];   // (28, 28, 65536) = [784][65536]
  const float* W  = (const float*)d_in[1];   // (28, 28, 28)
  const float* B  = (const float*)d_in[2];   // (28, 28, 1)
  float* out = (float*)d_out;                // (28, 28, 65536)
  unsigned short* A_ws = (unsigned short*)d_ws;  // 1.25 MB bf16 bcirc(W)

  build_A<<<(AWS_ELEMS + 255) / 256, 256, 0, stream>>>(W, A_ws);
  tnn_gemm<<<NWG, 256, 0, stream>>>(x, A_ws, B, out);
}